// Round 5
// baseline (434.333 us; speedup 1.0000x reference)
//
#include <hip/hip_runtime.h>
#include <hip/hip_bf16.h>
#include <cstddef>
#include <cstdint>

#define N_USER 100000
#define N_ITEM 100000
#define N_EDGE 1000000
#define IN_DIM 256
#define HID 128
#define OUT_DIM 16
#define LEAKY_SLOPE 0.01f
#define SRC_MASK 0x07FFFFFFu

// edge partition parameters
#define NC 98            // coarse buckets: dst>>10, 100000/1024 -> 0..97
#define CAPB 12288       // padded records per bucket (E[n]=10240, 20 sigma)
#define TILE 4096        // edges per part_coarse block (16/thread)

typedef __attribute__((ext_vector_type(8))) short bf16x8;
typedef __attribute__((ext_vector_type(4))) float f32x4;

static __device__ __forceinline__ unsigned short f2bf(float f) {
  // RTNE bf16 (matches __float2bfloat16 for normal values)
  unsigned int u = __float_as_uint(f);
  u = (u + 0x7FFFu + ((u >> 16) & 1u)) >> 16;
  return (unsigned short)u;
}

// ---------------------------------------------------------------------------
// split fp32 -> (hi, lo) bf16: a ~= hi + lo with ~16-bit effective mantissa.
// ---------------------------------------------------------------------------
static __device__ __forceinline__ void split8(const float4 x, const float4 y,
                                              bf16x8& hi, bf16x8& lo) {
  const float f[8] = {x.x, x.y, x.z, x.w, y.x, y.y, y.z, y.w};
#pragma unroll
  for (int j = 0; j < 8; ++j) {
    const unsigned u = __float_as_uint(f[j]);
    hi[j] = (short)(u >> 16);
    const float lf = f[j] - __uint_as_float(u & 0xffff0000u);
    lo[j] = (short)(__float_as_uint(lf) >> 16);
  }
}

// ---------------------------------------------------------------------------
// Pass A: coarse partition of edges into NC padded bucket regions.
// Record = src | (dst&1023)<<17.
// ---------------------------------------------------------------------------
__global__ __launch_bounds__(256)
void part_coarse(const int* __restrict__ srcA, const int* __restrict__ dstA,
                 const int* __restrict__ srcB, const int* __restrict__ dstB,
                 int* __restrict__ gcur, uint32_t* __restrict__ tmp, int n) {
  __shared__ uint32_t srec[TILE];       // 16 KB tile-sorted records
  __shared__ unsigned char sbkt[TILE];  // 4 KB bucket id per staged record
  __shared__ int hist[NC], lofs[NC], gbase[NC], lcur[NC];
  const int y = blockIdx.y, t = threadIdx.x;
  const int* __restrict__ src = y ? srcB : srcA;
  const int* __restrict__ dst = y ? dstB : dstA;
  const int e0 = blockIdx.x * TILE;
  const int ne = min(TILE, n - e0);

  for (int i = t; i < NC; i += 256) hist[i] = 0;
  __syncthreads();

  uint32_t rec[16];
  int bk[16];
#pragma unroll
  for (int q = 0; q < 16; ++q) {
    const int i = t + q * 256;
    if (i < ne) {
      const int d = dst[e0 + i];
      rec[q] = (uint32_t)src[e0 + i] | ((uint32_t)(d & 1023) << 17);
      bk[q] = d >> 10;
      atomicAdd(&hist[bk[q]], 1);
    } else {
      bk[q] = -1;
    }
  }
  __syncthreads();

  if (t == 0) {
    int run = 0;
#pragma unroll 1
    for (int i = 0; i < NC; ++i) { lofs[i] = run; run += hist[i]; }
  }
  __syncthreads();
  if (t < NC) {
    lcur[t] = 0;
    gbase[t] = atomicAdd(&gcur[y * NC + t], hist[t]);
  }
  __syncthreads();

#pragma unroll
  for (int q = 0; q < 16; ++q) {
    if (bk[q] >= 0) {
      const int p = lofs[bk[q]] + atomicAdd(&lcur[bk[q]], 1);
      srec[p] = rec[q];
      sbkt[p] = (unsigned char)bk[q];
    }
  }
  __syncthreads();

  uint32_t* __restrict__ outp = tmp + (size_t)y * NC * CAPB;
  for (int i = t; i < ne; i += 256) {
    const int b = sbkt[i];
    outp[(size_t)b * CAPB + gbase[b] + (i - lofs[b])] = srec[i];
  }
}

// ---------------------------------------------------------------------------
// Pass B: per (bucket, relation) block. LDS per-dst histogram + block scan ->
// emits cnt[]/pos[] -> in-L2 scatter of records to final dst order.
// ---------------------------------------------------------------------------
__global__ __launch_bounds__(256)
void part_fine(const uint32_t* __restrict__ tmp, const int* __restrict__ gcur,
               uint32_t* __restrict__ ebuf, int* __restrict__ pos,
               int* __restrict__ cnt) {
  __shared__ int dcnt[1024];
  __shared__ int sh[256];
  const int y = blockIdx.y, b = blockIdx.x, t = threadIdx.x;
  const int ne = gcur[y * NC + b];
  const uint32_t* __restrict__ in = tmp + ((size_t)y * NC + b) * CAPB;

  for (int i = t; i < 1024; i += 256) dcnt[i] = 0;
  __syncthreads();
  for (int i = t; i < ne; i += 256) atomicAdd(&dcnt[in[i] >> 17], 1);
  __syncthreads();

  const int bi = t * 4;
  const int v0 = dcnt[bi], v1 = dcnt[bi + 1], v2 = dcnt[bi + 2], v3 = dcnt[bi + 3];
  const int tsum = v0 + v1 + v2 + v3;
  sh[t] = tsum;
  __syncthreads();
#pragma unroll
  for (int d = 1; d < 256; d <<= 1) {
    const int x = (t >= d) ? sh[t - d] : 0;
    __syncthreads();
    sh[t] += x;
    __syncthreads();
  }
  const int p0 = sh[t] - tsum;
  const int p1 = p0 + v0, p2 = p1 + v1, p3 = p2 + v2;
  dcnt[bi] = p0; dcnt[bi + 1] = p1; dcnt[bi + 2] = p2; dcnt[bi + 3] = p3;

  const int drow0 = (b << 10) + bi;
  const int prel = b * CAPB;
  int* __restrict__ cw = cnt + (size_t)y * N_USER;
  int* __restrict__ pw = pos + (size_t)y * N_USER;
  if (drow0 + 0 < N_USER) { cw[drow0 + 0] = v0; pw[drow0 + 0] = prel + p0; }
  if (drow0 + 1 < N_USER) { cw[drow0 + 1] = v1; pw[drow0 + 1] = prel + p1; }
  if (drow0 + 2 < N_USER) { cw[drow0 + 2] = v2; pw[drow0 + 2] = prel + p2; }
  if (drow0 + 3 < N_USER) { cw[drow0 + 3] = v3; pw[drow0 + 3] = prel + p3; }
  __syncthreads();

  uint32_t* __restrict__ outp = ebuf + ((size_t)y * NC + b) * CAPB;
  for (int i = t; i < ne; i += 256) {
    const uint32_t r = in[i];
    const int p = atomicAdd(&dcnt[r >> 17], 1);
    outp[p] = r & 0x1FFFFu;
  }
}

// ---------------------------------------------------------------------------
// Build fused layer-0 weight Wf0 = Win_user @ W0_clicks [256,128], pre-SPLIT
// into (hi,lo) bf16 and pre-SWIZZLED into MFMA B-fragment order, plus
// bf0 = bin_user @ W0_clicks + b0_clicks.
// ---------------------------------------------------------------------------
__global__ __launch_bounds__(256)
void make_wfuse0(const float* __restrict__ Win, const float* __restrict__ bin,
                 const float* __restrict__ W0, const float* __restrict__ b0,
                 unsigned short* __restrict__ Bswz, float* __restrict__ bf0) {
  const int t = threadIdx.x;
  const int r = blockIdx.x * 2 + (t >> 7);   // k index in [0,256)
  const int n = t & 127;                     // col in [0,128)
  const float* wr = Win + (size_t)r * HID;
  float s = 0.f;
#pragma unroll 8
  for (int m = 0; m < HID; ++m) s += wr[m] * W0[(size_t)m * HID + n];
  const unsigned u = __float_as_uint(s);
  const unsigned short hi = (unsigned short)(u >> 16);
  const float lf = s - __uint_as_float(u & 0xffff0000u);
  const unsigned short lo = (unsigned short)(__float_as_uint(lf) >> 16);
  const int kt = r >> 5, lh = (r >> 3) & 3, j = r & 7;
  const int nf = n >> 4, lane = lh * 16 + (n & 15);
  Bswz[(size_t)(kt * 16 + nf * 2) * 512 + lane * 8 + j] = hi;
  Bswz[(size_t)(kt * 16 + nf * 2 + 1) * 512 + lane * 8 + j] = lo;
  if (blockIdx.x == 0 && t < HID) {
    float s2 = b0[t];
    for (int m = 0; m < HID; ++m) s2 += bin[m] * W0[(size_t)m * HID + t];
    bf0[t] = s2;
  }
}

// ---------------------------------------------------------------------------
// Wh[M,128](bf16) = A[M,256](fp32) @ Wf0 + bf0 via split-bf16 MFMA.
// ---------------------------------------------------------------------------
__global__ __launch_bounds__(256, 2)
void gemm_feat_mfma(const float* __restrict__ A,
                    const unsigned short* __restrict__ Bswz,
                    const float* __restrict__ bias,
                    unsigned short* __restrict__ Wh, int M) {
  __shared__ unsigned short Bs[2][16384];   // 2 x 32 KB
  const int t = threadIdx.x;
  const int w = t >> 6, lane = t & 63;
  const int rowW = blockIdx.x * 128 + w * 32;
  const int lr = lane & 15;                 // row-in-frag / col-in-frag
  const int lk = (lane >> 4) << 3;          // k offset 0/8/16/24

  int r0 = rowW + lr;      if (r0 >= M) r0 = M - 1;
  int r1 = rowW + 16 + lr; if (r1 >= M) r1 = M - 1;
  const float* pa0 = A + (size_t)r0 * IN_DIM + lk;
  const float* pa1 = A + (size_t)r1 * IN_DIM + lk;

  float bv[8];
#pragma unroll
  for (int nf = 0; nf < 8; ++nf) bv[nf] = bias[nf * 16 + lr];

  f32x4 acc[2][8];
#pragma unroll
  for (int rf = 0; rf < 2; ++rf)
#pragma unroll
    for (int nf = 0; nf < 8; ++nf)
#pragma unroll
      for (int q = 0; q < 4; ++q) acc[rf][nf][q] = 0.f;

  float4 af[2][2][2][2];  // [buf][rf][ktl][half]

#define STAGE_B(c, buf)                                                        \
  {                                                                            \
    _Pragma("unroll")                                                          \
    for (int i = 0; i < 8; ++i)                                                \
      __builtin_amdgcn_global_load_lds(                                        \
          (const __attribute__((address_space(1))) unsigned int*)              \
              ((const char*)Bswz + (c) * 32768 + i * 4096 + t * 16),           \
          (__attribute__((address_space(3))) unsigned int*)                    \
              &Bs[buf][i * 2048 + w * 512],                                    \
          16, 0, 0);                                                           \
  }

#define LOAD_A(c, buf)                                                         \
  {                                                                            \
    _Pragma("unroll")                                                          \
    for (int ktl = 0; ktl < 2; ++ktl) {                                        \
      af[buf][0][ktl][0] = *(const float4*)(pa0 + (c) * 64 + ktl * 32);        \
      af[buf][0][ktl][1] = *(const float4*)(pa0 + (c) * 64 + ktl * 32 + 4);    \
      af[buf][1][ktl][0] = *(const float4*)(pa1 + (c) * 64 + ktl * 32);        \
      af[buf][1][ktl][1] = *(const float4*)(pa1 + (c) * 64 + ktl * 32 + 4);    \
    }                                                                          \
  }

  STAGE_B(0, 0)
  LOAD_A(0, 0)
  __syncthreads();   // drains vmcnt: Bs[0] + af[0] ready

#pragma unroll
  for (int c = 0; c < 4; ++c) {
    const int cb = c & 1;
    if (c < 3) {
      STAGE_B(c + 1, cb ^ 1)
      LOAD_A(c + 1, cb ^ 1)
    }
    bf16x8 ah[2][2], al[2][2];
#pragma unroll
    for (int rf = 0; rf < 2; ++rf)
#pragma unroll
      for (int ktl = 0; ktl < 2; ++ktl)
        split8(af[cb][rf][ktl][0], af[cb][rf][ktl][1], ah[rf][ktl], al[rf][ktl]);
#pragma unroll
    for (int ktl = 0; ktl < 2; ++ktl) {
#pragma unroll
      for (int nf = 0; nf < 8; ++nf) {
        const bf16x8 bh =
            *(const bf16x8*)&Bs[cb][(ktl * 16 + nf * 2) * 512 + lane * 8];
        const bf16x8 bl =
            *(const bf16x8*)&Bs[cb][(ktl * 16 + nf * 2 + 1) * 512 + lane * 8];
#pragma unroll
        for (int rf = 0; rf < 2; ++rf) {
          acc[rf][nf] = __builtin_amdgcn_mfma_f32_16x16x32_bf16(
              ah[rf][ktl], bh, acc[rf][nf], 0, 0, 0);
          acc[rf][nf] = __builtin_amdgcn_mfma_f32_16x16x32_bf16(
              ah[rf][ktl], bl, acc[rf][nf], 0, 0, 0);
          acc[rf][nf] = __builtin_amdgcn_mfma_f32_16x16x32_bf16(
              al[rf][ktl], bh, acc[rf][nf], 0, 0, 0);
        }
      }
    }
    __syncthreads();   // Bs[cb^1] staged; safe to reuse Bs[cb] next iter
  }
#undef STAGE_B
#undef LOAD_A

  // epilogue: C/D frag layout col=lane&15, row=(lane>>4)*4+i  (bf16 out)
#pragma unroll
  for (int rf = 0; rf < 2; ++rf) {
#pragma unroll
    for (int i = 0; i < 4; ++i) {
      const int row = rowW + rf * 16 + ((lane >> 4) << 2) + i;
      if (row < M) {
        unsigned short* op = Wh + (size_t)row * HID + lr;
#pragma unroll
        for (int nf = 0; nf < 8; ++nf) op[nf * 16] = f2bf(acc[rf][nf][i] + bv[nf]);
      }
    }
  }
}

// ---------------------------------------------------------------------------
// Wfuse[128,16] = W1 @ Wout ; bfuse[16] = b1 @ Wout + bout. One block.
// ---------------------------------------------------------------------------
__global__ __launch_bounds__(256)
void make_wfuse(const float* __restrict__ W1, const float* __restrict__ b1,
                const float* __restrict__ Wout, const float* __restrict__ bout,
                float* __restrict__ Wf, float* __restrict__ bf) {
  __shared__ float Ws[HID * OUT_DIM];
  const int t = threadIdx.x;
  {
    const float4* s0 = (const float4*)Wout;
    float4* dp = (float4*)Ws;
    dp[t]       = s0[t];
    dp[t + 256] = s0[t + 256];
  }
  __syncthreads();
  const int k  = t >> 1;
  const int j0 = (t & 1) * 8;
  const float* w1row = W1 + (size_t)k * HID;
  float acc[8] = {0.f, 0.f, 0.f, 0.f, 0.f, 0.f, 0.f, 0.f};
  for (int m = 0; m < HID; ++m) {
    const float a = w1row[m];
    const float* wr = &Ws[m * OUT_DIM + j0];
#pragma unroll
    for (int q = 0; q < 8; ++q) acc[q] += a * wr[q];
  }
#pragma unroll
  for (int q = 0; q < 8; ++q) Wf[(size_t)k * OUT_DIM + j0 + q] = acc[q];
  if (t < OUT_DIM) {
    float s = bout[t];
    for (int m = 0; m < HID; ++m) s += b1[m] * Ws[m * OUT_DIM + t];
    bf[t] = s;
  }
}

// ---------------------------------------------------------------------------
// helper: accumulate 8 bf16 (hi halves of uint4 words) into fp32
// ---------------------------------------------------------------------------
static __device__ __forceinline__ void acc_bf8(float* a, uint4 u) {
  a[0] += __uint_as_float(u.x << 16);
  a[1] += __uint_as_float(u.x & 0xffff0000u);
  a[2] += __uint_as_float(u.y << 16);
  a[3] += __uint_as_float(u.y & 0xffff0000u);
  a[4] += __uint_as_float(u.z << 16);
  a[5] += __uint_as_float(u.z & 0xffff0000u);
  a[6] += __uint_as_float(u.w << 16);
  a[7] += __uint_as_float(u.w & 0xffff0000u);
}

// ---------------------------------------------------------------------------
// FUSED gather-1 + leaky + 128->16 projection, one WAVE per dst item row.
// 64 lanes = 4 edge slots (g) x 16 channel-lanes (c, 8 ch each).
// h row lives entirely in registers; z[row,16] written directly (64 B).
// Wf fragment (8 k x 4 n per lane) preloaded into VGPRs, reused across rows.
// ---------------------------------------------------------------------------
__global__ __launch_bounds__(256)
void gather_z_fused(const unsigned short* __restrict__ bh,
                    const int* __restrict__ pos, const int* __restrict__ cnt,
                    const uint32_t* __restrict__ ebuf,
                    const float* __restrict__ Wf, float* __restrict__ z) {
  const int lane = threadIdx.x & 63;
  const int g = lane >> 4, c = lane & 15;
  const int wid = (blockIdx.x * 256 + threadIdx.x) >> 6;
  const int nw = gridDim.x * 4;
  float4 wfv[8];
#pragma unroll
  for (int j = 0; j < 8; ++j)
    wfv[j] = *(const float4*)&Wf[(c * 8 + j) * OUT_DIM + g * 4];

  for (int row = wid; row < N_ITEM; row += nw) {
    const int beg = pos[row];
    const int cn  = cnt[row];
    float acc[8] = {0.f, 0.f, 0.f, 0.f, 0.f, 0.f, 0.f, 0.f};
    for (int i = g; i < cn; i += 4) {
      const int s = (int)(ebuf[beg + i] & SRC_MASK);
      const uint4 v = *((const uint4*)(bh + (size_t)s * HID) + c);
      acc_bf8(acc, v);
    }
    // reduce over the 4 edge slots
#pragma unroll
    for (int j = 0; j < 8; ++j) {
      acc[j] += __shfl_xor(acc[j], 16);
      acc[j] += __shfl_xor(acc[j], 32);
    }
    const float inv = cn > 0 ? 1.0f / (float)cn : 0.0f;
    float zx = 0.f, zy = 0.f, zz = 0.f, zw = 0.f;
#pragma unroll
    for (int j = 0; j < 8; ++j) {
      float h = acc[j] * inv;
      h = h > 0.f ? h : LEAKY_SLOPE * h;
      zx += h * wfv[j].x; zy += h * wfv[j].y;
      zz += h * wfv[j].z; zw += h * wfv[j].w;
    }
    // reduce over the 16 channel lanes within each group
#pragma unroll
    for (int m = 1; m < 16; m <<= 1) {
      zx += __shfl_xor(zx, m);
      zy += __shfl_xor(zy, m);
      zz += __shfl_xor(zz, m);
      zw += __shfl_xor(zw, m);
    }
    if (c < 4) {
      const float zv = (c == 0) ? zx : (c == 1) ? zy : (c == 2) ? zz : zw;
      z[(size_t)row * OUT_DIM + g * 4 + c] = zv;
    }
  }
}

// ---------------------------------------------------------------------------
// gather-2: out[d,16] = mean(z[src]) + (cn>0 ? bfuse : bout).
// One WAVE per dst user row: 4 edge slots x 16 channels (divergence-free).
// ---------------------------------------------------------------------------
__global__ __launch_bounds__(256)
void gather_mean16_w(const float* __restrict__ z, const int* __restrict__ pos,
                     const int* __restrict__ cnt, const uint32_t* __restrict__ ebuf,
                     const float* __restrict__ bfuse, const float* __restrict__ bout,
                     float* __restrict__ out) {
  const int lane = threadIdx.x & 63;
  const int g = lane >> 4, c = lane & 15;
  const int wid = (blockIdx.x * 256 + threadIdx.x) >> 6;
  const int nw = gridDim.x * 4;
  const float bfv = bfuse[c], bov = bout[c];
  for (int row = wid; row < N_USER; row += nw) {
    const int beg = pos[row];
    const int cn  = cnt[row];
    float acc = 0.f;
    for (int i = g; i < cn; i += 4)
      acc += z[(size_t)(ebuf[beg + i] & SRC_MASK) * OUT_DIM + c];
    acc += __shfl_xor(acc, 16);
    acc += __shfl_xor(acc, 32);
    if (g == 0)
      out[(size_t)row * OUT_DIM + c] = cn > 0 ? acc / (float)cn + bfv : bov;
  }
}

// ---------------------------------------------------------------------------
extern "C" void kernel_launch(void* const* d_in, const int* in_sizes, int n_in,
                              void* d_out, int out_size, void* d_ws, size_t ws_size,
                              hipStream_t stream) {
  const float* feat_user  = (const float*)d_in[0];
  // d_in[1] feat_item : dead (never reaches the output)
  const int*   src_clicks = (const int*)d_in[2];
  const int*   dst_clicks = (const int*)d_in[3];
  const int*   src_cb     = (const int*)d_in[4];
  const int*   dst_cb     = (const int*)d_in[5];
  const float* Win_user   = (const float*)d_in[6];
  const float* bin_user   = (const float*)d_in[7];
  // d_in[8..9] Win_item/bin_item : dead
  const float* W0_clicks  = (const float*)d_in[10];
  const float* b0_clicks  = (const float*)d_in[11];
  // d_in[12..15] W0_cb/b0_cb/W1_clicks/b1_clicks : dead
  const float* W1_cb      = (const float*)d_in[16];
  const float* b1_cb      = (const float*)d_in[17];
  const float* Wout       = (const float*)d_in[18];
  const float* bout       = (const float*)d_in[19];
  float* out = (float*)d_out;

  const size_t SZ  = (size_t)N_USER * HID * sizeof(float);           // 51.2 MB
  const size_t SZH = (size_t)N_USER * HID * sizeof(unsigned short);  // 25.6 MB
  const size_t SZZ = (size_t)N_USER * OUT_DIM * sizeof(float);       // 6.4 MB
  char* ws = (char*)d_ws;
  // tmp (coarse-binned records) occupies the first region (dead after part_fine)
  uint32_t* tmp        = (uint32_t*)ws;                // [2][NC][CAPB] = 9.6 MB
  unsigned short* bh   = (unsigned short*)(ws + SZ);   // wh_u0 (bf16)
  float* z0            = (float*)(ws + SZ + SZH);      // z = h_i0 @ Wfuse
  // Bswz/bf0 overlap the z0 region: dead before gather_z_fused writes z0.
  unsigned short* Bswz = (unsigned short*)z0;                  // [64K] = 128 KB
  float* bf0v          = (float*)((char*)z0 + 131072);         // [128]
  float* Wf            = (float*)(ws + SZ + SZH + SZZ);        // [128,16]
  float* bf            = Wf + HID * OUT_DIM;                   // [16]
  int* cnt  = (int*)(bf + OUT_DIM);               // [2][100000] per-dst degree
  int* pos  = cnt + 2 * N_USER;                   // [2][100000] per-dst row beg
  int* gcur = pos + 2 * N_USER;                   // [2][NC] bucket fill counts
  uint32_t* ebuf = (uint32_t*)(gcur + 2 * NC + 12);  // [2][NC][CAPB] final

  const int GM  = (N_USER + 127) / 128;           // 782
  const int GP  = (N_EDGE + TILE - 1) / TILE;     // 245

  // --- 2-pass padded-bucket edge partition (both relations via y) ---
  hipMemsetAsync(gcur, 0, (size_t)2 * NC * sizeof(int), stream);
  part_coarse<<<dim3(GP, 2), 256, 0, stream>>>(src_clicks, dst_clicks,
                                               src_cb, dst_cb, gcur, tmp, N_EDGE);
  part_fine<<<dim3(NC, 2), 256, 0, stream>>>(tmp, gcur, ebuf, pos, cnt);

  // fused final projection: Wf = W1_cb @ Wout, bf = b1_cb @ Wout + bout
  make_wfuse<<<1, 256, 0, stream>>>(W1_cb, b1_cb, Wout, bout, Wf, bf);
  // fused input projection: Bswz = split/swizzled(Win_user @ W0_clicks),
  // bf0 = bin_user @ W0_clicks + b0_clicks
  make_wfuse0<<<128, 256, 0, stream>>>(Win_user, bin_user, W0_clicks, b0_clicks,
                                       Bswz, bf0v);

  // 1) wh_u0 = feat_user @ (Win@W0) + bf0  (split-bf16 MFMA) -> bh (bf16)
  gemm_feat_mfma<<<GM, 256, 0, stream>>>(feat_user, Bswz, bf0v, bh, N_USER);
  // 2) z0 = leaky(seg_mean over clicks) @ (W1_cb @ Wout)     -> z0 (fused)
  gather_z_fused<<<2048, 256, 0, stream>>>(bh, pos, cnt, ebuf, Wf, z0);
  // 3) out = seg_mean(z0 over clicked_by) + bias select      -> out
  gather_mean16_w<<<2048, 256, 0, stream>>>(z0, pos + N_USER, cnt + N_USER,
                                            ebuf + (size_t)NC * CAPB, bf, bout, out);
}

// Round 6
// 387.423 us; speedup vs baseline: 1.1211x; 1.1211x over previous
//
#include <hip/hip_runtime.h>
#include <hip/hip_bf16.h>
#include <cstddef>
#include <cstdint>

#define N_USER 100000
#define N_ITEM 100000
#define N_EDGE 1000000
#define IN_DIM 256
#define HID 128
#define OUT_DIM 16
#define LEAKY_SLOPE 0.01f
#define SRC_MASK 0x07FFFFFFu

// edge partition parameters
#define NC 98            // coarse buckets: dst>>10, 100000/1024 -> 0..97
#define CAPB 12288       // padded records per bucket (E[n]=10240, 20 sigma)
#define TILE 4096        // edges per part_coarse block (16/thread)

typedef __attribute__((ext_vector_type(8))) short bf16x8;
typedef __attribute__((ext_vector_type(4))) float f32x4;

static __device__ __forceinline__ unsigned short f2bf(float f) {
  // RTNE bf16 (matches __float2bfloat16 for normal values)
  unsigned int u = __float_as_uint(f);
  u = (u + 0x7FFFu + ((u >> 16) & 1u)) >> 16;
  return (unsigned short)u;
}

// ---------------------------------------------------------------------------
// split fp32 -> (hi, lo) bf16: a ~= hi + lo with ~16-bit effective mantissa.
// ---------------------------------------------------------------------------
static __device__ __forceinline__ void split8(const float4 x, const float4 y,
                                              bf16x8& hi, bf16x8& lo) {
  const float f[8] = {x.x, x.y, x.z, x.w, y.x, y.y, y.z, y.w};
#pragma unroll
  for (int j = 0; j < 8; ++j) {
    const unsigned u = __float_as_uint(f[j]);
    hi[j] = (short)(u >> 16);
    const float lf = f[j] - __uint_as_float(u & 0xffff0000u);
    lo[j] = (short)(__float_as_uint(lf) >> 16);
  }
}

// ---------------------------------------------------------------------------
// Pass A: coarse partition of edges into NC padded bucket regions.
// Record = src | (dst&1023)<<17.
// ---------------------------------------------------------------------------
__global__ __launch_bounds__(256)
void part_coarse(const int* __restrict__ srcA, const int* __restrict__ dstA,
                 const int* __restrict__ srcB, const int* __restrict__ dstB,
                 int* __restrict__ gcur, uint32_t* __restrict__ tmp, int n) {
  __shared__ uint32_t srec[TILE];       // 16 KB tile-sorted records
  __shared__ unsigned char sbkt[TILE];  // 4 KB bucket id per staged record
  __shared__ int hist[NC], lofs[NC], gbase[NC], lcur[NC];
  const int y = blockIdx.y, t = threadIdx.x;
  const int* __restrict__ src = y ? srcB : srcA;
  const int* __restrict__ dst = y ? dstB : dstA;
  const int e0 = blockIdx.x * TILE;
  const int ne = min(TILE, n - e0);

  for (int i = t; i < NC; i += 256) hist[i] = 0;
  __syncthreads();

  uint32_t rec[16];
  int bk[16];
#pragma unroll
  for (int q = 0; q < 16; ++q) {
    const int i = t + q * 256;
    if (i < ne) {
      const int d = dst[e0 + i];
      rec[q] = (uint32_t)src[e0 + i] | ((uint32_t)(d & 1023) << 17);
      bk[q] = d >> 10;
      atomicAdd(&hist[bk[q]], 1);
    } else {
      bk[q] = -1;
    }
  }
  __syncthreads();

  if (t == 0) {
    int run = 0;
#pragma unroll 1
    for (int i = 0; i < NC; ++i) { lofs[i] = run; run += hist[i]; }
  }
  __syncthreads();
  if (t < NC) {
    lcur[t] = 0;
    gbase[t] = atomicAdd(&gcur[y * NC + t], hist[t]);
  }
  __syncthreads();

#pragma unroll
  for (int q = 0; q < 16; ++q) {
    if (bk[q] >= 0) {
      const int p = lofs[bk[q]] + atomicAdd(&lcur[bk[q]], 1);
      srec[p] = rec[q];
      sbkt[p] = (unsigned char)bk[q];
    }
  }
  __syncthreads();

  uint32_t* __restrict__ outp = tmp + (size_t)y * NC * CAPB;
  for (int i = t; i < ne; i += 256) {
    const int b = sbkt[i];
    outp[(size_t)b * CAPB + gbase[b] + (i - lofs[b])] = srec[i];
  }
}

// ---------------------------------------------------------------------------
// Pass B: per (bucket, relation) block. LDS per-dst histogram + block scan ->
// emits cnt[]/pos[] -> in-L2 scatter of records to final dst order.
// ---------------------------------------------------------------------------
__global__ __launch_bounds__(256)
void part_fine(const uint32_t* __restrict__ tmp, const int* __restrict__ gcur,
               uint32_t* __restrict__ ebuf, int* __restrict__ pos,
               int* __restrict__ cnt) {
  __shared__ int dcnt[1024];
  __shared__ int sh[256];
  const int y = blockIdx.y, b = blockIdx.x, t = threadIdx.x;
  const int ne = gcur[y * NC + b];
  const uint32_t* __restrict__ in = tmp + ((size_t)y * NC + b) * CAPB;

  for (int i = t; i < 1024; i += 256) dcnt[i] = 0;
  __syncthreads();
  for (int i = t; i < ne; i += 256) atomicAdd(&dcnt[in[i] >> 17], 1);
  __syncthreads();

  const int bi = t * 4;
  const int v0 = dcnt[bi], v1 = dcnt[bi + 1], v2 = dcnt[bi + 2], v3 = dcnt[bi + 3];
  const int tsum = v0 + v1 + v2 + v3;
  sh[t] = tsum;
  __syncthreads();
#pragma unroll
  for (int d = 1; d < 256; d <<= 1) {
    const int x = (t >= d) ? sh[t - d] : 0;
    __syncthreads();
    sh[t] += x;
    __syncthreads();
  }
  const int p0 = sh[t] - tsum;
  const int p1 = p0 + v0, p2 = p1 + v1, p3 = p2 + v2;
  dcnt[bi] = p0; dcnt[bi + 1] = p1; dcnt[bi + 2] = p2; dcnt[bi + 3] = p3;

  const int drow0 = (b << 10) + bi;
  const int prel = b * CAPB;
  int* __restrict__ cw = cnt + (size_t)y * N_USER;
  int* __restrict__ pw = pos + (size_t)y * N_USER;
  if (drow0 + 0 < N_USER) { cw[drow0 + 0] = v0; pw[drow0 + 0] = prel + p0; }
  if (drow0 + 1 < N_USER) { cw[drow0 + 1] = v1; pw[drow0 + 1] = prel + p1; }
  if (drow0 + 2 < N_USER) { cw[drow0 + 2] = v2; pw[drow0 + 2] = prel + p2; }
  if (drow0 + 3 < N_USER) { cw[drow0 + 3] = v3; pw[drow0 + 3] = prel + p3; }
  __syncthreads();

  uint32_t* __restrict__ outp = ebuf + ((size_t)y * NC + b) * CAPB;
  for (int i = t; i < ne; i += 256) {
    const uint32_t r = in[i];
    const int p = atomicAdd(&dcnt[r >> 17], 1);
    outp[p] = r & 0x1FFFFu;
  }
}

// ---------------------------------------------------------------------------
// Build fused layer-0 weight Wf0 = Win_user @ W0_clicks [256,128], pre-SPLIT
// into (hi,lo) bf16 and pre-SWIZZLED into MFMA B-fragment order, plus
// bf0 = bin_user @ W0_clicks + b0_clicks.
// ---------------------------------------------------------------------------
__global__ __launch_bounds__(256)
void make_wfuse0(const float* __restrict__ Win, const float* __restrict__ bin,
                 const float* __restrict__ W0, const float* __restrict__ b0,
                 unsigned short* __restrict__ Bswz, float* __restrict__ bf0) {
  const int t = threadIdx.x;
  const int r = blockIdx.x * 2 + (t >> 7);   // k index in [0,256)
  const int n = t & 127;                     // col in [0,128)
  const float* wr = Win + (size_t)r * HID;
  float s = 0.f;
#pragma unroll 8
  for (int m = 0; m < HID; ++m) s += wr[m] * W0[(size_t)m * HID + n];
  const unsigned u = __float_as_uint(s);
  const unsigned short hi = (unsigned short)(u >> 16);
  const float lf = s - __uint_as_float(u & 0xffff0000u);
  const unsigned short lo = (unsigned short)(__float_as_uint(lf) >> 16);
  const int kt = r >> 5, lh = (r >> 3) & 3, j = r & 7;
  const int nf = n >> 4, lane = lh * 16 + (n & 15);
  Bswz[(size_t)(kt * 16 + nf * 2) * 512 + lane * 8 + j] = hi;
  Bswz[(size_t)(kt * 16 + nf * 2 + 1) * 512 + lane * 8 + j] = lo;
  if (blockIdx.x == 0 && t < HID) {
    float s2 = b0[t];
    for (int m = 0; m < HID; ++m) s2 += bin[m] * W0[(size_t)m * HID + t];
    bf0[t] = s2;
  }
}

// ---------------------------------------------------------------------------
// Wh[M,128](bf16) = A[M,256](fp32) @ Wf0 + bf0 via split-bf16 MFMA.
// ---------------------------------------------------------------------------
__global__ __launch_bounds__(256, 2)
void gemm_feat_mfma(const float* __restrict__ A,
                    const unsigned short* __restrict__ Bswz,
                    const float* __restrict__ bias,
                    unsigned short* __restrict__ Wh, int M) {
  __shared__ unsigned short Bs[2][16384];   // 2 x 32 KB
  const int t = threadIdx.x;
  const int w = t >> 6, lane = t & 63;
  const int rowW = blockIdx.x * 128 + w * 32;
  const int lr = lane & 15;                 // row-in-frag / col-in-frag
  const int lk = (lane >> 4) << 3;          // k offset 0/8/16/24

  int r0 = rowW + lr;      if (r0 >= M) r0 = M - 1;
  int r1 = rowW + 16 + lr; if (r1 >= M) r1 = M - 1;
  const float* pa0 = A + (size_t)r0 * IN_DIM + lk;
  const float* pa1 = A + (size_t)r1 * IN_DIM + lk;

  float bv[8];
#pragma unroll
  for (int nf = 0; nf < 8; ++nf) bv[nf] = bias[nf * 16 + lr];

  f32x4 acc[2][8];
#pragma unroll
  for (int rf = 0; rf < 2; ++rf)
#pragma unroll
    for (int nf = 0; nf < 8; ++nf)
#pragma unroll
      for (int q = 0; q < 4; ++q) acc[rf][nf][q] = 0.f;

  float4 af[2][2][2][2];  // [buf][rf][ktl][half]

#define STAGE_B(c, buf)                                                        \
  {                                                                            \
    _Pragma("unroll")                                                          \
    for (int i = 0; i < 8; ++i)                                                \
      __builtin_amdgcn_global_load_lds(                                        \
          (const __attribute__((address_space(1))) unsigned int*)              \
              ((const char*)Bswz + (c) * 32768 + i * 4096 + t * 16),           \
          (__attribute__((address_space(3))) unsigned int*)                    \
              &Bs[buf][i * 2048 + w * 512],                                    \
          16, 0, 0);                                                           \
  }

#define LOAD_A(c, buf)                                                         \
  {                                                                            \
    _Pragma("unroll")                                                          \
    for (int ktl = 0; ktl < 2; ++ktl) {                                        \
      af[buf][0][ktl][0] = *(const float4*)(pa0 + (c) * 64 + ktl * 32);        \
      af[buf][0][ktl][1] = *(const float4*)(pa0 + (c) * 64 + ktl * 32 + 4);    \
      af[buf][1][ktl][0] = *(const float4*)(pa1 + (c) * 64 + ktl * 32);        \
      af[buf][1][ktl][1] = *(const float4*)(pa1 + (c) * 64 + ktl * 32 + 4);    \
    }                                                                          \
  }

  STAGE_B(0, 0)
  LOAD_A(0, 0)
  __syncthreads();   // drains vmcnt: Bs[0] + af[0] ready

#pragma unroll
  for (int c = 0; c < 4; ++c) {
    const int cb = c & 1;
    if (c < 3) {
      STAGE_B(c + 1, cb ^ 1)
      LOAD_A(c + 1, cb ^ 1)
    }
    bf16x8 ah[2][2], al[2][2];
#pragma unroll
    for (int rf = 0; rf < 2; ++rf)
#pragma unroll
      for (int ktl = 0; ktl < 2; ++ktl)
        split8(af[cb][rf][ktl][0], af[cb][rf][ktl][1], ah[rf][ktl], al[rf][ktl]);
#pragma unroll
    for (int ktl = 0; ktl < 2; ++ktl) {
#pragma unroll
      for (int nf = 0; nf < 8; ++nf) {
        const bf16x8 bh =
            *(const bf16x8*)&Bs[cb][(ktl * 16 + nf * 2) * 512 + lane * 8];
        const bf16x8 bl =
            *(const bf16x8*)&Bs[cb][(ktl * 16 + nf * 2 + 1) * 512 + lane * 8];
#pragma unroll
        for (int rf = 0; rf < 2; ++rf) {
          acc[rf][nf] = __builtin_amdgcn_mfma_f32_16x16x32_bf16(
              ah[rf][ktl], bh, acc[rf][nf], 0, 0, 0);
          acc[rf][nf] = __builtin_amdgcn_mfma_f32_16x16x32_bf16(
              ah[rf][ktl], bl, acc[rf][nf], 0, 0, 0);
          acc[rf][nf] = __builtin_amdgcn_mfma_f32_16x16x32_bf16(
              al[rf][ktl], bh, acc[rf][nf], 0, 0, 0);
        }
      }
    }
    __syncthreads();   // Bs[cb^1] staged; safe to reuse Bs[cb] next iter
  }
#undef STAGE_B
#undef LOAD_A

  // epilogue: C/D frag layout col=lane&15, row=(lane>>4)*4+i  (bf16 out)
#pragma unroll
  for (int rf = 0; rf < 2; ++rf) {
#pragma unroll
    for (int i = 0; i < 4; ++i) {
      const int row = rowW + rf * 16 + ((lane >> 4) << 2) + i;
      if (row < M) {
        unsigned short* op = Wh + (size_t)row * HID + lr;
#pragma unroll
        for (int nf = 0; nf < 8; ++nf) op[nf * 16] = f2bf(acc[rf][nf][i] + bv[nf]);
      }
    }
  }
}

// ---------------------------------------------------------------------------
// Wfuse[128,16] = W1 @ Wout ; bfuse[16] = b1 @ Wout + bout. One block.
// ---------------------------------------------------------------------------
__global__ __launch_bounds__(256)
void make_wfuse(const float* __restrict__ W1, const float* __restrict__ b1,
                const float* __restrict__ Wout, const float* __restrict__ bout,
                float* __restrict__ Wf, float* __restrict__ bf) {
  __shared__ float Ws[HID * OUT_DIM];
  const int t = threadIdx.x;
  {
    const float4* s0 = (const float4*)Wout;
    float4* dp = (float4*)Ws;
    dp[t]       = s0[t];
    dp[t + 256] = s0[t + 256];
  }
  __syncthreads();
  const int k  = t >> 1;
  const int j0 = (t & 1) * 8;
  const float* w1row = W1 + (size_t)k * HID;
  float acc[8] = {0.f, 0.f, 0.f, 0.f, 0.f, 0.f, 0.f, 0.f};
  for (int m = 0; m < HID; ++m) {
    const float a = w1row[m];
    const float* wr = &Ws[m * OUT_DIM + j0];
#pragma unroll
    for (int q = 0; q < 8; ++q) acc[q] += a * wr[q];
  }
#pragma unroll
  for (int q = 0; q < 8; ++q) Wf[(size_t)k * OUT_DIM + j0 + q] = acc[q];
  if (t < OUT_DIM) {
    float s = bout[t];
    for (int m = 0; m < HID; ++m) s += b1[m] * Ws[m * OUT_DIM + t];
    bf[t] = s;
  }
}

// ---------------------------------------------------------------------------
// helper: accumulate 8 bf16 (hi halves of uint4 words) into fp32
// ---------------------------------------------------------------------------
static __device__ __forceinline__ void acc_bf8(float* a, uint4 u) {
  a[0] += __uint_as_float(u.x << 16);
  a[1] += __uint_as_float(u.x & 0xffff0000u);
  a[2] += __uint_as_float(u.y << 16);
  a[3] += __uint_as_float(u.y & 0xffff0000u);
  a[4] += __uint_as_float(u.z << 16);
  a[5] += __uint_as_float(u.z & 0xffff0000u);
  a[6] += __uint_as_float(u.w << 16);
  a[7] += __uint_as_float(u.w & 0xffff0000u);
}

// ---------------------------------------------------------------------------
// FUSED gather-1 + leaky + 128->16 projection, 16 rows/block, 16 lanes/row
// (the high-MLP structure: 8-way/4-way unrolled edge loop, up to 8 gather
// loads in flight per lane). h row -> LDS -> block-level projection phase:
// thread (r,j) computes z[r][j] = sum_k hs[r][k]*Wf[k][j]; h reads are
// 16-lane broadcasts, Wf reads are lane-stride-4B conflict-free.
// ---------------------------------------------------------------------------
__global__ __launch_bounds__(256)
void gather_z_fused2(const unsigned short* __restrict__ bh,
                     const int* __restrict__ pos, const int* __restrict__ cnt,
                     const uint32_t* __restrict__ ebuf,
                     const float* __restrict__ Wf, float* __restrict__ z) {
  __shared__ float hs[16 * 132];        // 16 rows x 128 (+4 pad)
  __shared__ float ws[HID * OUT_DIM];   // 8 KB staged Wf
  const int t = threadIdx.x;
  {
    const float4* s0 = (const float4*)Wf;
    float4* dp = (float4*)ws;
    dp[t]       = s0[t];
    dp[t + 256] = s0[t + 256];
  }
  const int r = t >> 4;
  const int c = t & 15;
  const int row = blockIdx.x * 16 + r;
  const int beg = pos[row];
  const int cn  = cnt[row];
  float acc[8] = {0.f, 0.f, 0.f, 0.f, 0.f, 0.f, 0.f, 0.f};
  int i = 0;
  for (; i + 8 <= cn; i += 8) {
    int s[8];
#pragma unroll
    for (int q = 0; q < 8; ++q) s[q] = (int)(ebuf[beg + i + q] & SRC_MASK);
    uint4 v[8];
#pragma unroll
    for (int q = 0; q < 8; ++q) v[q] = *((const uint4*)(bh + (size_t)s[q] * HID) + c);
#pragma unroll
    for (int q = 0; q < 8; ++q) acc_bf8(acc, v[q]);
  }
  for (; i + 4 <= cn; i += 4) {
    int s[4];
#pragma unroll
    for (int q = 0; q < 4; ++q) s[q] = (int)(ebuf[beg + i + q] & SRC_MASK);
    uint4 v[4];
#pragma unroll
    for (int q = 0; q < 4; ++q) v[q] = *((const uint4*)(bh + (size_t)s[q] * HID) + c);
#pragma unroll
    for (int q = 0; q < 4; ++q) acc_bf8(acc, v[q]);
  }
  for (; i < cn; ++i) {
    const int s = (int)(ebuf[beg + i] & SRC_MASK);
    const uint4 v = *((const uint4*)(bh + (size_t)s * HID) + c);
    acc_bf8(acc, v);
  }
  const float inv = cn > 0 ? 1.0f / (float)cn : 0.0f;
  float h[8];
#pragma unroll
  for (int q = 0; q < 8; ++q) {
    float v = acc[q] * inv;
    h[q] = v > 0.f ? v : LEAKY_SLOPE * v;
  }
  *(float4*)&hs[r * 132 + c * 8]     = make_float4(h[0], h[1], h[2], h[3]);
  *(float4*)&hs[r * 132 + c * 8 + 4] = make_float4(h[4], h[5], h[6], h[7]);
  __syncthreads();
  // projection phase: thread (r, j)
  const int j = c;
  float s = 0.f;
  const float* hp = &hs[r * 132];
#pragma unroll 8
  for (int k = 0; k < HID; ++k) s += hp[k] * ws[k * OUT_DIM + j];
  z[(size_t)row * OUT_DIM + j] = s;
}

// ---------------------------------------------------------------------------
// gather-2: out[d,16] = mean(z[src]) + (cn>0 ? bfuse : bout)
// 16 lanes per dst row (one float each), 16 rows per block, 4-way unroll.
// ---------------------------------------------------------------------------
__global__ __launch_bounds__(256)
void gather_mean16(const float* __restrict__ z, const int* __restrict__ pos,
                   const int* __restrict__ cnt, const uint32_t* __restrict__ ebuf,
                   const float* __restrict__ bfuse, const float* __restrict__ bout,
                   float* __restrict__ out) {
  const int row = blockIdx.x * 16 + (threadIdx.x >> 4);
  const int c = threadIdx.x & 15;
  const int beg = pos[row];
  const int cn  = cnt[row];
  float acc = 0.f;
  int i = 0;
  for (; i + 4 <= cn; i += 4) {
    const int s0 = (int)(ebuf[beg + i]     & SRC_MASK);
    const int s1 = (int)(ebuf[beg + i + 1] & SRC_MASK);
    const int s2 = (int)(ebuf[beg + i + 2] & SRC_MASK);
    const int s3 = (int)(ebuf[beg + i + 3] & SRC_MASK);
    const float v0 = z[(size_t)s0 * OUT_DIM + c];
    const float v1 = z[(size_t)s1 * OUT_DIM + c];
    const float v2 = z[(size_t)s2 * OUT_DIM + c];
    const float v3 = z[(size_t)s3 * OUT_DIM + c];
    acc += v0 + v1 + v2 + v3;
  }
  for (; i < cn; ++i) {
    const int s = (int)(ebuf[beg + i] & SRC_MASK);
    acc += z[(size_t)s * OUT_DIM + c];
  }
  float o;
  if (cn > 0) o = acc * (1.0f / (float)cn) + bfuse[c];
  else        o = bout[c];
  out[(size_t)row * OUT_DIM + c] = o;
}

// ---------------------------------------------------------------------------
extern "C" void kernel_launch(void* const* d_in, const int* in_sizes, int n_in,
                              void* d_out, int out_size, void* d_ws, size_t ws_size,
                              hipStream_t stream) {
  const float* feat_user  = (const float*)d_in[0];
  // d_in[1] feat_item : dead (never reaches the output)
  const int*   src_clicks = (const int*)d_in[2];
  const int*   dst_clicks = (const int*)d_in[3];
  const int*   src_cb     = (const int*)d_in[4];
  const int*   dst_cb     = (const int*)d_in[5];
  const float* Win_user   = (const float*)d_in[6];
  const float* bin_user   = (const float*)d_in[7];
  // d_in[8..9] Win_item/bin_item : dead
  const float* W0_clicks  = (const float*)d_in[10];
  const float* b0_clicks  = (const float*)d_in[11];
  // d_in[12..15] W0_cb/b0_cb/W1_clicks/b1_clicks : dead
  const float* W1_cb      = (const float*)d_in[16];
  const float* b1_cb      = (const float*)d_in[17];
  const float* Wout       = (const float*)d_in[18];
  const float* bout       = (const float*)d_in[19];
  float* out = (float*)d_out;

  const size_t SZ  = (size_t)N_USER * HID * sizeof(float);           // 51.2 MB
  const size_t SZH = (size_t)N_USER * HID * sizeof(unsigned short);  // 25.6 MB
  const size_t SZZ = (size_t)N_USER * OUT_DIM * sizeof(float);       // 6.4 MB
  char* ws = (char*)d_ws;
  // tmp (coarse-binned records) occupies the first region (dead after part_fine)
  uint32_t* tmp        = (uint32_t*)ws;                // [2][NC][CAPB] = 9.6 MB
  unsigned short* bh   = (unsigned short*)(ws + SZ);   // wh_u0 (bf16)
  float* z0            = (float*)(ws + SZ + SZH);      // z = h_i0 @ Wfuse
  // Bswz/bf0 overlap the z0 region: dead before gather_z_fused2 writes z0.
  unsigned short* Bswz = (unsigned short*)z0;                  // [64K] = 128 KB
  float* bf0v          = (float*)((char*)z0 + 131072);         // [128]
  float* Wf            = (float*)(ws + SZ + SZH + SZZ);        // [128,16]
  float* bf            = Wf + HID * OUT_DIM;                   // [16]
  int* cnt  = (int*)(bf + OUT_DIM);               // [2][100000] per-dst degree
  int* pos  = cnt + 2 * N_USER;                   // [2][100000] per-dst row beg
  int* gcur = pos + 2 * N_USER;                   // [2][NC] bucket fill counts
  uint32_t* ebuf = (uint32_t*)(gcur + 2 * NC + 12);  // [2][NC][CAPB] final

  const int G16 = N_USER / 16;                    // 6250
  const int GM  = (N_USER + 127) / 128;           // 782
  const int GP  = (N_EDGE + TILE - 1) / TILE;     // 245

  // --- 2-pass padded-bucket edge partition (both relations via y) ---
  hipMemsetAsync(gcur, 0, (size_t)2 * NC * sizeof(int), stream);
  part_coarse<<<dim3(GP, 2), 256, 0, stream>>>(src_clicks, dst_clicks,
                                               src_cb, dst_cb, gcur, tmp, N_EDGE);
  part_fine<<<dim3(NC, 2), 256, 0, stream>>>(tmp, gcur, ebuf, pos, cnt);

  // fused final projection: Wf = W1_cb @ Wout, bf = b1_cb @ Wout + bout
  make_wfuse<<<1, 256, 0, stream>>>(W1_cb, b1_cb, Wout, bout, Wf, bf);
  // fused input projection: Bswz = split/swizzled(Win_user @ W0_clicks),
  // bf0 = bin_user @ W0_clicks + b0_clicks
  make_wfuse0<<<128, 256, 0, stream>>>(Win_user, bin_user, W0_clicks, b0_clicks,
                                       Bswz, bf0v);

  // 1) wh_u0 = feat_user @ (Win@W0) + bf0  (split-bf16 MFMA) -> bh (bf16)
  gemm_feat_mfma<<<GM, 256, 0, stream>>>(feat_user, Bswz, bf0v, bh, N_USER);
  // 2) z0 = leaky(seg_mean over clicks) @ (W1_cb @ Wout)     -> z0 (fused)
  gather_z_fused2<<<G16, 256, 0, stream>>>(bh, pos, cnt, ebuf, Wf, z0);
  // 3) out = seg_mean(z0 over clicked_by) + bias select      -> out
  gather_mean16<<<G16, 256, 0, stream>>>(z0, pos + N_USER, cnt + N_USER,
                                         ebuf + (size_t)NC * CAPB, bf, bout, out);
}

// Round 7
// 353.122 us; speedup vs baseline: 1.2300x; 1.0971x over previous
//
#include <hip/hip_runtime.h>
#include <hip/hip_bf16.h>
#include <cstddef>
#include <cstdint>

#define N_USER 100000
#define N_ITEM 100000
#define N_EDGE 1000000
#define IN_DIM 256
#define HID 128
#define OUT_DIM 16
#define LEAKY_SLOPE 0.01f
#define SRC_MASK 0x07FFFFFFu

// edge partition parameters
#define NC 98            // coarse buckets: dst>>10, 100000/1024 -> 0..97
#define CAPB 12288       // padded records per bucket (E[n]=10240, 20 sigma)
#define TILE 4096        // edges per part_coarse block (16/thread)
#define GP 245           // ceil(N_EDGE / TILE)
#define GM 782           // ceil(N_USER / 128)

typedef __attribute__((ext_vector_type(8))) short bf16x8;
typedef __attribute__((ext_vector_type(4))) float f32x4;

static __device__ __forceinline__ unsigned short f2bf(float f) {
  // RTNE bf16 (matches __float2bfloat16 for normal values)
  unsigned int u = __float_as_uint(f);
  u = (u + 0x7FFFu + ((u >> 16) & 1u)) >> 16;
  return (unsigned short)u;
}

// ---------------------------------------------------------------------------
// split fp32 -> (hi, lo) bf16: a ~= hi + lo with ~16-bit effective mantissa.
// ---------------------------------------------------------------------------
static __device__ __forceinline__ void split8(const float4 x, const float4 y,
                                              bf16x8& hi, bf16x8& lo) {
  const float f[8] = {x.x, x.y, x.z, x.w, y.x, y.y, y.z, y.w};
#pragma unroll
  for (int j = 0; j < 8; ++j) {
    const unsigned u = __float_as_uint(f[j]);
    hi[j] = (short)(u >> 16);
    const float lf = f[j] - __uint_as_float(u & 0xffff0000u);
    lo[j] = (short)(__float_as_uint(lf) >> 16);
  }
}

// ===========================================================================
// prep1 = part_coarse (490 blocks) ∪ make_wfuse0 (128) ∪ make_wfuse (1)
// — independent stages fused into one launch for overlap. LDS union 21.7 KB.
// ===========================================================================
union P1Shared {
  struct {
    uint32_t srec[TILE];       // 16 KB tile-sorted records
    unsigned char sbkt[TILE];  // 4 KB bucket ids
    int hist[NC], lofs[NC], gbase[NC], lcur[NC];
  } a;
  float wsbuf[HID * OUT_DIM];  // 8 KB (make_wfuse)
};

// ---- part_coarse body: coarse partition into NC padded bucket regions.
// Record = src | (dst&1023)<<17.
static __device__ void part_coarse_body(const int* __restrict__ src,
                                        const int* __restrict__ dst,
                                        int* __restrict__ gcur,
                                        uint32_t* __restrict__ tmp,
                                        int y, int b, P1Shared& S) {
  const int t = threadIdx.x;
  const int e0 = b * TILE;
  const int ne = min(TILE, N_EDGE - e0);

  for (int i = t; i < NC; i += 256) S.a.hist[i] = 0;
  __syncthreads();

  uint32_t rec[16];
  int bk[16];
#pragma unroll
  for (int q = 0; q < 16; ++q) {
    const int i = t + q * 256;
    if (i < ne) {
      const int d = dst[e0 + i];
      rec[q] = (uint32_t)src[e0 + i] | ((uint32_t)(d & 1023) << 17);
      bk[q] = d >> 10;
      atomicAdd(&S.a.hist[bk[q]], 1);
    } else {
      bk[q] = -1;
    }
  }
  __syncthreads();

  if (t == 0) {
    int run = 0;
#pragma unroll 1
    for (int i = 0; i < NC; ++i) { S.a.lofs[i] = run; run += S.a.hist[i]; }
  }
  __syncthreads();
  if (t < NC) {
    S.a.lcur[t] = 0;
    S.a.gbase[t] = atomicAdd(&gcur[y * NC + t], S.a.hist[t]);
  }
  __syncthreads();

#pragma unroll
  for (int q = 0; q < 16; ++q) {
    if (bk[q] >= 0) {
      const int p = S.a.lofs[bk[q]] + atomicAdd(&S.a.lcur[bk[q]], 1);
      S.a.srec[p] = rec[q];
      S.a.sbkt[p] = (unsigned char)bk[q];
    }
  }
  __syncthreads();

  uint32_t* __restrict__ outp = tmp + (size_t)y * NC * CAPB;
  for (int i = t; i < ne; i += 256) {
    const int b2 = S.a.sbkt[i];
    outp[(size_t)b2 * CAPB + S.a.gbase[b2] + (i - S.a.lofs[b2])] = S.a.srec[i];
  }
}

// ---- make_wfuse0 body: Bswz = split/swizzled(Win @ W0), bf0 = bin@W0 + b0.
static __device__ void make_wfuse0_body(const float* __restrict__ Win,
                                        const float* __restrict__ bin,
                                        const float* __restrict__ W0,
                                        const float* __restrict__ b0,
                                        unsigned short* __restrict__ Bswz,
                                        float* __restrict__ bf0, int bx) {
  const int t = threadIdx.x;
  const int r = bx * 2 + (t >> 7);   // k index in [0,256)
  const int n = t & 127;             // col in [0,128)
  const float* wr = Win + (size_t)r * HID;
  float s = 0.f;
#pragma unroll 8
  for (int m = 0; m < HID; ++m) s += wr[m] * W0[(size_t)m * HID + n];
  const unsigned u = __float_as_uint(s);
  const unsigned short hi = (unsigned short)(u >> 16);
  const float lf = s - __uint_as_float(u & 0xffff0000u);
  const unsigned short lo = (unsigned short)(__float_as_uint(lf) >> 16);
  const int kt = r >> 5, lh = (r >> 3) & 3, j = r & 7;
  const int nf = n >> 4, lane = lh * 16 + (n & 15);
  Bswz[(size_t)(kt * 16 + nf * 2) * 512 + lane * 8 + j] = hi;
  Bswz[(size_t)(kt * 16 + nf * 2 + 1) * 512 + lane * 8 + j] = lo;
  if (bx == 0 && t < HID) {
    float s2 = b0[t];
    for (int m = 0; m < HID; ++m) s2 += bin[m] * W0[(size_t)m * HID + t];
    bf0[t] = s2;
  }
}

// ---- make_wfuse body: Wf = W1 @ Wout ; bf = b1 @ Wout + bout.
static __device__ void make_wfuse_body(const float* __restrict__ W1,
                                       const float* __restrict__ b1,
                                       const float* __restrict__ Wout,
                                       const float* __restrict__ bout,
                                       float* __restrict__ Wf,
                                       float* __restrict__ bf, P1Shared& S) {
  const int t = threadIdx.x;
  {
    const float4* s0 = (const float4*)Wout;
    float4* dp = (float4*)S.wsbuf;
    dp[t]       = s0[t];
    dp[t + 256] = s0[t + 256];
  }
  __syncthreads();
  const int k  = t >> 1;
  const int j0 = (t & 1) * 8;
  const float* w1row = W1 + (size_t)k * HID;
  float acc[8] = {0.f, 0.f, 0.f, 0.f, 0.f, 0.f, 0.f, 0.f};
  for (int m = 0; m < HID; ++m) {
    const float a = w1row[m];
    const float* wr = &S.wsbuf[m * OUT_DIM + j0];
#pragma unroll
    for (int q = 0; q < 8; ++q) acc[q] += a * wr[q];
  }
#pragma unroll
  for (int q = 0; q < 8; ++q) Wf[(size_t)k * OUT_DIM + j0 + q] = acc[q];
  if (t < OUT_DIM) {
    float s = bout[t];
    for (int m = 0; m < HID; ++m) s += b1[m] * S.wsbuf[m * OUT_DIM + t];
    bf[t] = s;
  }
}

__global__ __launch_bounds__(256)
void prep1(const int* __restrict__ srcA, const int* __restrict__ dstA,
           const int* __restrict__ srcB, const int* __restrict__ dstB,
           int* __restrict__ gcur, uint32_t* __restrict__ tmp,
           const float* __restrict__ Win, const float* __restrict__ bin,
           const float* __restrict__ W0, const float* __restrict__ b0,
           unsigned short* __restrict__ Bswz, float* __restrict__ bf0,
           const float* __restrict__ W1, const float* __restrict__ b1,
           const float* __restrict__ Wout, const float* __restrict__ bout,
           float* __restrict__ Wf, float* __restrict__ bf) {
  __shared__ P1Shared S;
  const int bx = blockIdx.x;
  if (bx < 2 * GP) {
    const int y = bx >= GP ? 1 : 0;
    part_coarse_body(y ? srcB : srcA, y ? dstB : dstA, gcur, tmp, y, bx - y * GP, S);
  } else if (bx < 2 * GP + 128) {
    make_wfuse0_body(Win, bin, W0, b0, Bswz, bf0, bx - 2 * GP);
  } else {
    make_wfuse_body(W1, b1, Wout, bout, Wf, bf, S);
  }
}

// ===========================================================================
// prep2 = part_fine (196 blocks) ∪ gemm_feat_mfma (782 blocks).
// part_fine hides under the MFMA GEMM. LDS union 64 KB, 2 blocks/CU.
// ===========================================================================
union P2Shared {
  struct { unsigned short Bs[2][16384]; } g;   // 64 KB (gemm)
  struct { int dcnt[1024]; int sh[256]; } f;   // 5 KB (part_fine)
};

// ---- part_fine body: per (bucket,relation): LDS histogram + scan -> cnt/pos
// -> in-L2 scatter of records to final dst order.
static __device__ void part_fine_body(const uint32_t* __restrict__ tmp,
                                      const int* __restrict__ gcur,
                                      uint32_t* __restrict__ ebuf,
                                      int* __restrict__ pos,
                                      int* __restrict__ cnt,
                                      int y, int b, P2Shared& S) {
  const int t = threadIdx.x;
  const int ne = gcur[y * NC + b];
  const uint32_t* __restrict__ in = tmp + ((size_t)y * NC + b) * CAPB;

  for (int i = t; i < 1024; i += 256) S.f.dcnt[i] = 0;
  __syncthreads();
  for (int i = t; i < ne; i += 256) atomicAdd(&S.f.dcnt[in[i] >> 17], 1);
  __syncthreads();

  const int bi = t * 4;
  const int v0 = S.f.dcnt[bi], v1 = S.f.dcnt[bi + 1];
  const int v2 = S.f.dcnt[bi + 2], v3 = S.f.dcnt[bi + 3];
  const int tsum = v0 + v1 + v2 + v3;
  S.f.sh[t] = tsum;
  __syncthreads();
#pragma unroll
  for (int d = 1; d < 256; d <<= 1) {
    const int x = (t >= d) ? S.f.sh[t - d] : 0;
    __syncthreads();
    S.f.sh[t] += x;
    __syncthreads();
  }
  const int p0 = S.f.sh[t] - tsum;
  const int p1 = p0 + v0, p2 = p1 + v1, p3 = p2 + v2;
  S.f.dcnt[bi] = p0; S.f.dcnt[bi + 1] = p1;
  S.f.dcnt[bi + 2] = p2; S.f.dcnt[bi + 3] = p3;

  const int drow0 = (b << 10) + bi;
  const int prel = b * CAPB;
  int* __restrict__ cw = cnt + (size_t)y * N_USER;
  int* __restrict__ pw = pos + (size_t)y * N_USER;
  if (drow0 + 0 < N_USER) { cw[drow0 + 0] = v0; pw[drow0 + 0] = prel + p0; }
  if (drow0 + 1 < N_USER) { cw[drow0 + 1] = v1; pw[drow0 + 1] = prel + p1; }
  if (drow0 + 2 < N_USER) { cw[drow0 + 2] = v2; pw[drow0 + 2] = prel + p2; }
  if (drow0 + 3 < N_USER) { cw[drow0 + 3] = v3; pw[drow0 + 3] = prel + p3; }
  __syncthreads();

  uint32_t* __restrict__ outp = ebuf + ((size_t)y * NC + b) * CAPB;
  for (int i = t; i < ne; i += 256) {
    const uint32_t r = in[i];
    const int p = atomicAdd(&S.f.dcnt[r >> 17], 1);
    outp[p] = r & 0x1FFFFu;
  }
}

// ---- gemm body: Wh[M,128](bf16) = A[M,256](fp32) @ Wf0 + bf0, split-bf16 MFMA.
static __device__ void gemm_feat_body(const float* __restrict__ A,
                                      const unsigned short* __restrict__ Bswz,
                                      const float* __restrict__ bias,
                                      unsigned short* __restrict__ Wh,
                                      int M, int bg, P2Shared& S) {
  const int t = threadIdx.x;
  const int w = t >> 6, lane = t & 63;
  const int rowW = bg * 128 + w * 32;
  const int lr = lane & 15;                 // row-in-frag / col-in-frag
  const int lk = (lane >> 4) << 3;          // k offset 0/8/16/24

  int r0 = rowW + lr;      if (r0 >= M) r0 = M - 1;
  int r1 = rowW + 16 + lr; if (r1 >= M) r1 = M - 1;
  const float* pa0 = A + (size_t)r0 * IN_DIM + lk;
  const float* pa1 = A + (size_t)r1 * IN_DIM + lk;

  float bv[8];
#pragma unroll
  for (int nf = 0; nf < 8; ++nf) bv[nf] = bias[nf * 16 + lr];

  f32x4 acc[2][8];
#pragma unroll
  for (int rf = 0; rf < 2; ++rf)
#pragma unroll
    for (int nf = 0; nf < 8; ++nf)
#pragma unroll
      for (int q = 0; q < 4; ++q) acc[rf][nf][q] = 0.f;

  float4 af[2][2][2][2];  // [buf][rf][ktl][half]

#define STAGE_B(c, buf)                                                        \
  {                                                                            \
    _Pragma("unroll")                                                          \
    for (int i = 0; i < 8; ++i)                                                \
      __builtin_amdgcn_global_load_lds(                                        \
          (const __attribute__((address_space(1))) unsigned int*)              \
              ((const char*)Bswz + (c) * 32768 + i * 4096 + t * 16),           \
          (__attribute__((address_space(3))) unsigned int*)                    \
              &S.g.Bs[buf][i * 2048 + w * 512],                                \
          16, 0, 0);                                                           \
  }

#define LOAD_A(c, buf)                                                         \
  {                                                                            \
    _Pragma("unroll")                                                          \
    for (int ktl = 0; ktl < 2; ++ktl) {                                        \
      af[buf][0][ktl][0] = *(const float4*)(pa0 + (c) * 64 + ktl * 32);        \
      af[buf][0][ktl][1] = *(const float4*)(pa0 + (c) * 64 + ktl * 32 + 4);    \
      af[buf][1][ktl][0] = *(const float4*)(pa1 + (c) * 64 + ktl * 32);        \
      af[buf][1][ktl][1] = *(const float4*)(pa1 + (c) * 64 + ktl * 32 + 4);    \
    }                                                                          \
  }

  STAGE_B(0, 0)
  LOAD_A(0, 0)
  __syncthreads();   // drains vmcnt: Bs[0] + af[0] ready

#pragma unroll
  for (int c = 0; c < 4; ++c) {
    const int cb = c & 1;
    if (c < 3) {
      STAGE_B(c + 1, cb ^ 1)
      LOAD_A(c + 1, cb ^ 1)
    }
    bf16x8 ah[2][2], al[2][2];
#pragma unroll
    for (int rf = 0; rf < 2; ++rf)
#pragma unroll
      for (int ktl = 0; ktl < 2; ++ktl)
        split8(af[cb][rf][ktl][0], af[cb][rf][ktl][1], ah[rf][ktl], al[rf][ktl]);
#pragma unroll
    for (int ktl = 0; ktl < 2; ++ktl) {
#pragma unroll
      for (int nf = 0; nf < 8; ++nf) {
        const bf16x8 bh =
            *(const bf16x8*)&S.g.Bs[cb][(ktl * 16 + nf * 2) * 512 + lane * 8];
        const bf16x8 bl =
            *(const bf16x8*)&S.g.Bs[cb][(ktl * 16 + nf * 2 + 1) * 512 + lane * 8];
#pragma unroll
        for (int rf = 0; rf < 2; ++rf) {
          acc[rf][nf] = __builtin_amdgcn_mfma_f32_16x16x32_bf16(
              ah[rf][ktl], bh, acc[rf][nf], 0, 0, 0);
          acc[rf][nf] = __builtin_amdgcn_mfma_f32_16x16x32_bf16(
              ah[rf][ktl], bl, acc[rf][nf], 0, 0, 0);
          acc[rf][nf] = __builtin_amdgcn_mfma_f32_16x16x32_bf16(
              al[rf][ktl], bh, acc[rf][nf], 0, 0, 0);
        }
      }
    }
    __syncthreads();   // Bs[cb^1] staged; safe to reuse Bs[cb] next iter
  }
#undef STAGE_B
#undef LOAD_A

  // epilogue: C/D frag layout col=lane&15, row=(lane>>4)*4+i  (bf16 out)
#pragma unroll
  for (int rf = 0; rf < 2; ++rf) {
#pragma unroll
    for (int i = 0; i < 4; ++i) {
      const int row = rowW + rf * 16 + ((lane >> 4) << 2) + i;
      if (row < M) {
        unsigned short* op = Wh + (size_t)row * HID + lr;
#pragma unroll
        for (int nf = 0; nf < 8; ++nf) op[nf * 16] = f2bf(acc[rf][nf][i] + bv[nf]);
      }
    }
  }
}

__global__ __launch_bounds__(256, 2)
void prep2(const uint32_t* __restrict__ tmp, const int* __restrict__ gcur,
           uint32_t* __restrict__ ebuf, int* __restrict__ pos,
           int* __restrict__ cnt,
           const float* __restrict__ A, const unsigned short* __restrict__ Bswz,
           const float* __restrict__ bf0, unsigned short* __restrict__ Wh) {
  __shared__ P2Shared S;
  const int bx = blockIdx.x;
  if (bx < 2 * NC) {
    const int y = bx >= NC ? 1 : 0;
    part_fine_body(tmp, gcur, ebuf, pos, cnt, y, bx - y * NC, S);
  } else {
    gemm_feat_body(A, Bswz, bf0, Wh, N_USER, bx - 2 * NC, S);
  }
}

// ---------------------------------------------------------------------------
// helper: accumulate 8 bf16 (hi halves of uint4 words) into fp32
// ---------------------------------------------------------------------------
static __device__ __forceinline__ void acc_bf8(float* a, uint4 u) {
  a[0] += __uint_as_float(u.x << 16);
  a[1] += __uint_as_float(u.x & 0xffff0000u);
  a[2] += __uint_as_float(u.y << 16);
  a[3] += __uint_as_float(u.y & 0xffff0000u);
  a[4] += __uint_as_float(u.z << 16);
  a[5] += __uint_as_float(u.z & 0xffff0000u);
  a[6] += __uint_as_float(u.w << 16);
  a[7] += __uint_as_float(u.w & 0xffff0000u);
}

// ---------------------------------------------------------------------------
// FUSED gather-1 + leaky + 128->16 projection, 16 rows/block, 16 lanes/row
// (8-way/4-way unrolled edge loop = up to 8 gather loads in flight/lane).
// h rows -> LDS -> block projection: z[r][j] = sum_k hs[r][k]*Wf[k][j].
// ---------------------------------------------------------------------------
__global__ __launch_bounds__(256)
void gather_z_fused2(const unsigned short* __restrict__ bh,
                     const int* __restrict__ pos, const int* __restrict__ cnt,
                     const uint32_t* __restrict__ ebuf,
                     const float* __restrict__ Wf, float* __restrict__ z) {
  __shared__ float hs[16 * 132];        // 16 rows x 128 (+4 pad)
  __shared__ float ws[HID * OUT_DIM];   // 8 KB staged Wf
  const int t = threadIdx.x;
  {
    const float4* s0 = (const float4*)Wf;
    float4* dp = (float4*)ws;
    dp[t]       = s0[t];
    dp[t + 256] = s0[t + 256];
  }
  const int r = t >> 4;
  const int c = t & 15;
  const int row = blockIdx.x * 16 + r;
  const int beg = pos[row];
  const int cn  = cnt[row];
  float acc[8] = {0.f, 0.f, 0.f, 0.f, 0.f, 0.f, 0.f, 0.f};
  int i = 0;
  for (; i + 8 <= cn; i += 8) {
    int s[8];
#pragma unroll
    for (int q = 0; q < 8; ++q) s[q] = (int)(ebuf[beg + i + q] & SRC_MASK);
    uint4 v[8];
#pragma unroll
    for (int q = 0; q < 8; ++q) v[q] = *((const uint4*)(bh + (size_t)s[q] * HID) + c);
#pragma unroll
    for (int q = 0; q < 8; ++q) acc_bf8(acc, v[q]);
  }
  for (; i + 4 <= cn; i += 4) {
    int s[4];
#pragma unroll
    for (int q = 0; q < 4; ++q) s[q] = (int)(ebuf[beg + i + q] & SRC_MASK);
    uint4 v[4];
#pragma unroll
    for (int q = 0; q < 4; ++q) v[q] = *((const uint4*)(bh + (size_t)s[q] * HID) + c);
#pragma unroll
    for (int q = 0; q < 4; ++q) acc_bf8(acc, v[q]);
  }
  for (; i < cn; ++i) {
    const int s = (int)(ebuf[beg + i] & SRC_MASK);
    const uint4 v = *((const uint4*)(bh + (size_t)s * HID) + c);
    acc_bf8(acc, v);
  }
  const float inv = cn > 0 ? 1.0f / (float)cn : 0.0f;
  float h[8];
#pragma unroll
  for (int q = 0; q < 8; ++q) {
    float v = acc[q] * inv;
    h[q] = v > 0.f ? v : LEAKY_SLOPE * v;
  }
  *(float4*)&hs[r * 132 + c * 8]     = make_float4(h[0], h[1], h[2], h[3]);
  *(float4*)&hs[r * 132 + c * 8 + 4] = make_float4(h[4], h[5], h[6], h[7]);
  __syncthreads();
  // projection phase: thread (r, j)
  const int j = c;
  float s = 0.f;
  const float* hp = &hs[r * 132];
#pragma unroll 8
  for (int k = 0; k < HID; ++k) s += hp[k] * ws[k * OUT_DIM + j];
  z[(size_t)row * OUT_DIM + j] = s;
}

// ---------------------------------------------------------------------------
// gather-2: out[d,16] = mean(z[src]) + (cn>0 ? bfuse : bout)
// 16 lanes per dst row, 16 rows per block, 8-way + 4-way unroll.
// ---------------------------------------------------------------------------
__global__ __launch_bounds__(256)
void gather_mean16(const float* __restrict__ z, const int* __restrict__ pos,
                   const int* __restrict__ cnt, const uint32_t* __restrict__ ebuf,
                   const float* __restrict__ bfuse, const float* __restrict__ bout,
                   float* __restrict__ out) {
  const int row = blockIdx.x * 16 + (threadIdx.x >> 4);
  const int c = threadIdx.x & 15;
  const int beg = pos[row];
  const int cn  = cnt[row];
  float acc = 0.f;
  int i = 0;
  for (; i + 8 <= cn; i += 8) {
    int s[8];
#pragma unroll
    for (int q = 0; q < 8; ++q) s[q] = (int)(ebuf[beg + i + q] & SRC_MASK);
    float v[8];
#pragma unroll
    for (int q = 0; q < 8; ++q) v[q] = z[(size_t)s[q] * OUT_DIM + c];
#pragma unroll
    for (int q = 0; q < 8; ++q) acc += v[q];
  }
  for (; i + 4 <= cn; i += 4) {
    int s[4];
#pragma unroll
    for (int q = 0; q < 4; ++q) s[q] = (int)(ebuf[beg + i + q] & SRC_MASK);
    float v[4];
#pragma unroll
    for (int q = 0; q < 4; ++q) v[q] = z[(size_t)s[q] * OUT_DIM + c];
#pragma unroll
    for (int q = 0; q < 4; ++q) acc += v[q];
  }
  for (; i < cn; ++i) {
    const int s = (int)(ebuf[beg + i] & SRC_MASK);
    acc += z[(size_t)s * OUT_DIM + c];
  }
  float o;
  if (cn > 0) o = acc * (1.0f / (float)cn) + bfuse[c];
  else        o = bout[c];
  out[(size_t)row * OUT_DIM + c] = o;
}

// ---------------------------------------------------------------------------
extern "C" void kernel_launch(void* const* d_in, const int* in_sizes, int n_in,
                              void* d_out, int out_size, void* d_ws, size_t ws_size,
                              hipStream_t stream) {
  const float* feat_user  = (const float*)d_in[0];
  // d_in[1] feat_item : dead (never reaches the output)
  const int*   src_clicks = (const int*)d_in[2];
  const int*   dst_clicks = (const int*)d_in[3];
  const int*   src_cb     = (const int*)d_in[4];
  const int*   dst_cb     = (const int*)d_in[5];
  const float* Win_user   = (const float*)d_in[6];
  const float* bin_user   = (const float*)d_in[7];
  // d_in[8..9] Win_item/bin_item : dead
  const float* W0_clicks  = (const float*)d_in[10];
  const float* b0_clicks  = (const float*)d_in[11];
  // d_in[12..15] W0_cb/b0_cb/W1_clicks/b1_clicks : dead
  const float* W1_cb      = (const float*)d_in[16];
  const float* b1_cb      = (const float*)d_in[17];
  const float* Wout       = (const float*)d_in[18];
  const float* bout       = (const float*)d_in[19];
  float* out = (float*)d_out;

  const size_t SZ  = (size_t)N_USER * HID * sizeof(float);           // 51.2 MB
  const size_t SZH = (size_t)N_USER * HID * sizeof(unsigned short);  // 25.6 MB
  const size_t SZZ = (size_t)N_USER * OUT_DIM * sizeof(float);       // 6.4 MB
  char* ws = (char*)d_ws;
  // tmp (coarse-binned records) occupies the first region (dead after prep2)
  uint32_t* tmp        = (uint32_t*)ws;                // [2][NC][CAPB] = 9.6 MB
  unsigned short* bh   = (unsigned short*)(ws + SZ);   // wh_u0 (bf16)
  float* z0            = (float*)(ws + SZ + SZH);      // z = h_i0 @ Wfuse
  // Bswz/bf0 overlap the z0 region: dead before gather_z_fused2 writes z0.
  unsigned short* Bswz = (unsigned short*)z0;                  // [64K] = 128 KB
  float* bf0v          = (float*)((char*)z0 + 131072);         // [128]
  float* Wf            = (float*)(ws + SZ + SZH + SZZ);        // [128,16]
  float* bf            = Wf + HID * OUT_DIM;                   // [16]
  int* cnt  = (int*)(bf + OUT_DIM);               // [2][100000] per-dst degree
  int* pos  = cnt + 2 * N_USER;                   // [2][100000] per-dst row beg
  int* gcur = pos + 2 * N_USER;                   // [2][NC] bucket fill counts
  uint32_t* ebuf = (uint32_t*)(gcur + 2 * NC + 12);  // [2][NC][CAPB] final

  const int G16 = N_USER / 16;                    // 6250

  hipMemsetAsync(gcur, 0, (size_t)2 * NC * sizeof(int), stream);
  // prep1: part_coarse (490) ∪ make_wfuse0 (128) ∪ make_wfuse (1)
  prep1<<<2 * GP + 128 + 1, 256, 0, stream>>>(
      src_clicks, dst_clicks, src_cb, dst_cb, gcur, tmp,
      Win_user, bin_user, W0_clicks, b0_clicks, Bswz, bf0v,
      W1_cb, b1_cb, Wout, bout, Wf, bf);
  // prep2: part_fine (196) ∪ gemm_feat_mfma (782)
  prep2<<<2 * NC + GM, 256, 0, stream>>>(tmp, gcur, ebuf, pos, cnt,
                                         feat_user, Bswz, bf0v, bh);
  // gather-1 fused with leaky + 128->16 projection
  gather_z_fused2<<<G16, 256, 0, stream>>>(bh, pos, cnt, ebuf, Wf, z0);
  // gather-2: out = seg_mean(z0 over clicked_by) + bias select
  gather_mean16<<<G16, 256, 0, stream>>>(z0, pos + N_USER, cnt + N_USER,
                                         ebuf + (size_t)NC * CAPB, bf, bout, out);
}